// Round 2
// baseline (548.219 us; speedup 1.0000x reference)
//
#include <hip/hip_runtime.h>
#include <hip/hip_bf16.h>
#include <stdint.h>

#define NN 100000
#define NE 1600000
#define DD 128
#define NEG 0.01f
#define SCAN_B 392   // ceil(NN/256)

typedef __attribute__((ext_vector_type(8))) short short8;
typedef __attribute__((ext_vector_type(4))) float floatx4;
typedef __attribute__((ext_vector_type(2))) float floatx2;
typedef __attribute__((ext_vector_type(4))) uint32_t uint32x4;

__device__ __forceinline__ float bf2f(uint16_t u){
  return __uint_as_float(((uint32_t)u) << 16);
}
__device__ __forceinline__ uint16_t f2bf(float f){
  uint32_t i = __float_as_uint(f);
  return (uint16_t)((i + 0x7FFFu + ((i >> 16) & 1u)) >> 16);  // RNE
}
__device__ __forceinline__ float lrelu(float x){ return fmaxf(x, NEG * x); }

// ---------------- dtype detect: are float tensors f32 or bf16? ----------------
// Low 16 bits of each 32-bit word: for bf16-pair data it's a valid bf16 of an
// N(0,1) sample (exp field in [100,134] essentially always); for f32 data it's
// uniform mantissa bits (~14% hit that range). flag=1 => f32 inputs.
__global__ void k_detect(const uint32_t* __restrict__ xw, int* __restrict__ flag){
  int lane = threadIdx.x;
  uint32_t w = xw[lane];
  uint32_t e = (w >> 7) & 0xFFu;
  int plaus = (e >= 100u && e <= 134u) ? 1 : 0;
  unsigned long long b = __ballot(plaus);
  if (lane == 0) flag[0] = (__popcll(b) >= 48) ? 0 : 1;
}

// ---------------- CSR build ----------------
__global__ void k_count(const int* __restrict__ dst, int* __restrict__ deg){
  int e = blockIdx.x * 256 + threadIdx.x;
  if (e < NE) atomicAdd(&deg[dst[e]], 1);
}

__global__ void k_scan_a(const int* __restrict__ deg, float* __restrict__ dis,
                         int* __restrict__ bsum){
  __shared__ int sm[256];
  int i = blockIdx.x * 256 + threadIdx.x;
  int v = 0;
  if (i < NN){ v = deg[i]; dis[i] = rsqrtf((float)(v + 1)); }
  sm[threadIdx.x] = v;
  __syncthreads();
  for (int s = 128; s > 0; s >>= 1){
    if (threadIdx.x < s) sm[threadIdx.x] += sm[threadIdx.x + s];
    __syncthreads();
  }
  if (threadIdx.x == 0) bsum[blockIdx.x] = sm[0];
}

__global__ void k_scan_b(int* __restrict__ bsum){
  __shared__ int sm[512];
  int t = threadIdx.x;
  int v = (t < SCAN_B) ? bsum[t] : 0;
  sm[t] = v;
  __syncthreads();
  for (int s = 1; s < 512; s <<= 1){
    int add = (t >= s) ? sm[t - s] : 0;
    __syncthreads();
    sm[t] += add;
    __syncthreads();
  }
  if (t < SCAN_B) bsum[t] = sm[t] - v;   // exclusive
}

__global__ void k_scan_c(const int* __restrict__ deg, const int* __restrict__ bofs,
                         int* __restrict__ rowstart, int* __restrict__ cursor){
  __shared__ int sm[256];
  int t = threadIdx.x;
  int i = blockIdx.x * 256 + t;
  int v = (i < NN) ? deg[i] : 0;
  sm[t] = v;
  __syncthreads();
  for (int s = 1; s < 256; s <<= 1){
    int add = (t >= s) ? sm[t - s] : 0;
    __syncthreads();
    sm[t] += add;
    __syncthreads();
  }
  int excl = sm[t] - v + bofs[blockIdx.x];
  if (i < NN){ rowstart[i] = excl; cursor[i] = excl; }
  if (blockIdx.x == 0 && t == 0) rowstart[NN] = NE;
}

__global__ void k_fill(const int* __restrict__ src, const int* __restrict__ dst,
                       int* __restrict__ cursor, int* __restrict__ csr){
  int e = blockIdx.x * 256 + threadIdx.x;
  if (e < NE){
    int d = dst[e];
    int p = atomicAdd(&cursor[d], 1);
    csr[p] = src[e];
  }
}

// ---------------- weight transpose (+dtype convert): WT[c*128+k] = W[k][c] ----
__global__ void k_wt(const void* __restrict__ W, uint16_t* __restrict__ WT,
                     const int* __restrict__ flag){
  int idx = blockIdx.x * 256 + threadIdx.x;   // 64 blocks -> 16384
  int c = idx >> 7, k = idx & 127;
  WT[idx] = flag[0] ? f2bf(((const float*)W)[k * DD + c])
                    : ((const uint16_t*)W)[k * DD + c];
}

// bb[0..127] = b1 (bf16), bb[128..255] = b2 (bf16)
__global__ void k_bias(const void* __restrict__ b1, const void* __restrict__ b2,
                       uint16_t* __restrict__ bb, const int* __restrict__ flag){
  int t = threadIdx.x;   // 256
  const void* src = (t < 128) ? b1 : b2;
  int i = t & 127;
  bb[t] = flag[0] ? f2bf(((const float*)src)[i]) : ((const uint16_t*)src)[i];
}

// ---------------- X -> canonical bf16 copy ----------------
__global__ void k_cvt(const void* __restrict__ X, uint16_t* __restrict__ XB,
                      const int* __restrict__ flag){
  int i8 = blockIdx.x * 256 + threadIdx.x;    // 16-byte chunk of XB; 6250*256 = exact
  if (flag[0]){
    const floatx4* xf = (const floatx4*)X;
    floatx4 u = xf[i8 * 2], v = xf[i8 * 2 + 1];
    uint32x4 o;
    o.x = (uint32_t)f2bf(u.x) | ((uint32_t)f2bf(u.y) << 16);
    o.y = (uint32_t)f2bf(u.z) | ((uint32_t)f2bf(u.w) << 16);
    o.z = (uint32_t)f2bf(v.x) | ((uint32_t)f2bf(v.y) << 16);
    o.w = (uint32_t)f2bf(v.z) | ((uint32_t)f2bf(v.w) << 16);
    ((uint32x4*)XB)[i8] = o;
  } else {
    ((uint32x4*)XB)[i8] = ((const uint32x4*)X)[i8];
  }
}

// ---------------- GEMM: H = X * W (bf16 MFMA 16x16x32) ----------------
__global__ __launch_bounds__(256) void k_gemm(const uint16_t* __restrict__ X,
                                              const uint16_t* __restrict__ WT,
                                              uint16_t* __restrict__ H){
  __shared__ uint16_t lwt[128 * 136];   // +8 shorts pad -> 2-way bank alias (free)
  int t = threadIdx.x;
  const uint32_t* wt32 = (const uint32_t*)WT;
  #pragma unroll
  for (int i = 0; i < 32; i++){
    int uidx = t + 256 * i;
    uint32_t w2 = wt32[uidx];
    int el = uidx * 2;
    int c = el >> 7, k = el & 127;
    *(uint32_t*)&lwt[c * 136 + k] = w2;
  }
  __syncthreads();

  int wave = t >> 6, lane = t & 63;
  int m = lane & 15, q = lane >> 4;
  int rowbase = blockIdx.x * 64 + wave * 16;
  int ar = rowbase + m;
  if (ar >= NN) ar = 0;
  const short8* xrow = (const short8*)(X + (size_t)ar * DD);
  short8 a0 = xrow[q], a1 = xrow[q + 4], a2 = xrow[q + 8], a3 = xrow[q + 12];

  #pragma unroll
  for (int nt = 0; nt < 8; nt++){
    int c = nt * 16 + m;
    const uint16_t* bp = &lwt[c * 136 + q * 8];
    floatx4 acc = {0.f, 0.f, 0.f, 0.f};
    acc = __builtin_amdgcn_mfma_f32_16x16x32_bf16(a0, *(const short8*)(bp +  0), acc, 0, 0, 0);
    acc = __builtin_amdgcn_mfma_f32_16x16x32_bf16(a1, *(const short8*)(bp + 32), acc, 0, 0, 0);
    acc = __builtin_amdgcn_mfma_f32_16x16x32_bf16(a2, *(const short8*)(bp + 64), acc, 0, 0, 0);
    acc = __builtin_amdgcn_mfma_f32_16x16x32_bf16(a3, *(const short8*)(bp + 96), acc, 0, 0, 0);
    #pragma unroll
    for (int r = 0; r < 4; r++){
      int row = rowbase + q * 4 + r;
      if (row < NN) H[(size_t)row * DD + c] = f2bf(acc[r]);
    }
  }
}

// ---------------- aggregation: one wave per node, CSR gather ----------------
__global__ __launch_bounds__(256) void k_agg(const uint16_t* __restrict__ H,
                                             const int* __restrict__ rowstart,
                                             const int* __restrict__ csr,
                                             const float* __restrict__ dis,
                                             const uint16_t* __restrict__ bias,
                                             void* __restrict__ OUT,
                                             const int* __restrict__ flag,
                                             int is_final){
  int wave = threadIdx.x >> 6, lane = threadIdx.x & 63;
  int n = blockIdx.x * 4 + wave;
  if (n >= NN) return;
  float dn = dis[n];
  int beg = rowstart[n], end = rowstart[n + 1];
  uint32_t h2 = ((const uint32_t*)(H + (size_t)n * DD))[lane];
  float ss = dn * dn;
  float a0 = bf2f((uint16_t)(h2 & 0xffffu)) * ss;
  float a1 = bf2f((uint16_t)(h2 >> 16)) * ss;
  for (int j0 = beg; j0 < end; j0 += 64){
    int cnt = min(64, end - j0);
    int sj = 0; float dj = 0.f;
    if (lane < cnt){ sj = csr[j0 + lane]; dj = dis[sj]; }
    for (int jj = 0; jj < cnt; jj++){
      int s = __shfl(sj, jj);
      float coef = __shfl(dj, jj) * dn;
      uint32_t v = ((const uint32_t*)(H + (size_t)s * DD))[lane];
      a0 = fmaf(bf2f((uint16_t)(v & 0xffffu)), coef, a0);
      a1 = fmaf(bf2f((uint16_t)(v >> 16)), coef, a1);
    }
  }
  uint32_t b2 = ((const uint32_t*)bias)[lane];
  a0 = lrelu(a0 + bf2f((uint16_t)(b2 & 0xffffu)));
  a1 = lrelu(a1 + bf2f((uint16_t)(b2 >> 16)));
  if (is_final && flag[0]){
    floatx2 o = {a0, a1};
    ((floatx2*)((float*)OUT + (size_t)n * DD))[lane] = o;
  } else {
    ((uint32_t*)((uint16_t*)OUT + (size_t)n * DD))[lane] =
        (uint32_t)f2bf(a0) | ((uint32_t)f2bf(a1) << 16);
  }
}

extern "C" void kernel_launch(void* const* d_in, const int* in_sizes, int n_in,
                              void* d_out, int out_size, void* d_ws, size_t ws_size,
                              hipStream_t stream){
  const void* x  = d_in[0];
  const void* W1 = d_in[1];
  const void* b1 = d_in[2];
  const void* W2 = d_in[3];
  const void* b2 = d_in[4];
  const int* ei   = (const int*)d_in[5];
  const int* esrc = ei;
  const int* edst = ei + NE;

  char* ws = (char*)d_ws;
  int*      deg      = (int*)(ws + 0);                     // 400,000 B
  float*    dis      = (float*)(ws + 512ull * 1024);       // 400,000 B
  int*      rowstart = (int*)(ws + 1024ull * 1024);        // 400,004 B
  int*      cursor   = (int*)(ws + 1536ull * 1024);        // 400,000 B
  int*      bsum     = (int*)(ws + 2048ull * 1024);        // 1,568 B
  int*      flag     = (int*)(ws + 2052ull * 1024);        // 4 B
  uint16_t* WT1      = (uint16_t*)(ws + 2056ull * 1024);   // 32,768 B
  uint16_t* WT2      = (uint16_t*)(ws + 2090ull * 1024);   // 32,768 B
  uint16_t* bb       = (uint16_t*)(ws + 2124ull * 1024);   // 512 B
  int*      csr      = (int*)(ws + 2176ull * 1024);        // 6,400,000 B
  uint16_t* hA       = (uint16_t*)(ws + 8448ull * 1024);   // 25,600,000 B
  uint16_t* xb       = (uint16_t*)(ws + 33792ull * 1024);  // 25,600,000 B (also hB)
  uint16_t* hB       = xb;   // xb dead after gemm1; hB written by agg1 afterwards

  hipMemsetAsync(deg, 0, NN * sizeof(int), stream);
  k_detect<<<1, 64, 0, stream>>>((const uint32_t*)x, flag);
  k_count <<<NE / 256, 256, 0, stream>>>(edst, deg);
  k_scan_a<<<SCAN_B, 256, 0, stream>>>(deg, dis, bsum);
  k_scan_b<<<1, 512, 0, stream>>>(bsum);
  k_scan_c<<<SCAN_B, 256, 0, stream>>>(deg, bsum, rowstart, cursor);
  k_fill  <<<NE / 256, 256, 0, stream>>>(esrc, edst, cursor, csr);
  k_wt    <<<64, 256, 0, stream>>>(W1, WT1, flag);
  k_wt    <<<64, 256, 0, stream>>>(W2, WT2, flag);
  k_bias  <<<1, 256, 0, stream>>>(b1, b2, bb, flag);
  k_cvt   <<<6250, 256, 0, stream>>>(x, xb, flag);

  k_gemm<<<(NN + 63) / 64, 256, 0, stream>>>(xb, WT1, hA);
  k_agg <<<NN / 4, 256, 0, stream>>>(hA, rowstart, csr, dis, bb, hB, flag, 0);
  k_gemm<<<(NN + 63) / 64, 256, 0, stream>>>(hB, WT2, hA);
  k_agg <<<NN / 4, 256, 0, stream>>>(hA, rowstart, csr, dis, bb + 128, d_out, flag, 1);
}

// Round 3
// 397.624 us; speedup vs baseline: 1.3787x; 1.3787x over previous
//
#include <hip/hip_runtime.h>
#include <hip/hip_bf16.h>
#include <stdint.h>

#define NN 100000
#define NE 1600000
#define DD 128
#define NEG 0.01f
#define NB 196        // coarse buckets of 512 nodes (dst>>9)
#define EPB 4096      // edges per block in hist/scatter
#define NBLK1 391     // ceil(NE/EPB)

typedef __attribute__((ext_vector_type(8))) short short8;
typedef __attribute__((ext_vector_type(4))) float floatx4;
typedef __attribute__((ext_vector_type(2))) float floatx2;
typedef __attribute__((ext_vector_type(4))) uint32_t uint32x4;

__device__ __forceinline__ float bf2f(uint16_t u){
  return __uint_as_float(((uint32_t)u) << 16);
}
__device__ __forceinline__ uint16_t f2bf(float f){
  uint32_t i = __float_as_uint(f);
  return (uint16_t)((i + 0x7FFFu + ((i >> 16) & 1u)) >> 16);  // RNE
}
__device__ __forceinline__ float lrelu(float x){ return fmaxf(x, NEG * x); }

// ---------------- dtype detect: are float tensors f32 or bf16? ----------------
__global__ void k_detect(const uint32_t* __restrict__ xw, int* __restrict__ flag){
  int lane = threadIdx.x;
  uint32_t w = xw[lane];
  uint32_t e = (w >> 7) & 0xFFu;
  int plaus = (e >= 100u && e <= 134u) ? 1 : 0;
  unsigned long long b = __ballot(plaus);
  if (lane == 0) flag[0] = (__popcll(b) >= 48) ? 0 : 1;
}

// ---------------- CSR build: deterministic two-level counting sort ------------
// Pass 1: per-block coarse histogram (bucket = dst>>9). No global atomics.
__global__ __launch_bounds__(256) void k_hist(const int* __restrict__ dst,
                                              int* __restrict__ ghist){
  __shared__ int lh[NB];
  int t = threadIdx.x, b = blockIdx.x;
  if (t < NB) lh[t] = 0;
  __syncthreads();
  #pragma unroll
  for (int i = 0; i < 16; i++){
    int e = b * EPB + i * 256 + t;
    if (e < NE) atomicAdd(&lh[dst[e] >> 9], 1);
  }
  __syncthreads();
  if (t < NB) ghist[t * NBLK1 + b] = lh[t];
}

// Pass 2a: per-bucket exclusive scan over blocks (in-place) + bucket totals.
__global__ __launch_bounds__(512) void k_bscan(int* __restrict__ ghist,
                                               int* __restrict__ btotal){
  __shared__ int sm[512];
  int t = threadIdx.x, bkt = blockIdx.x;
  int v = (t < NBLK1) ? ghist[bkt * NBLK1 + t] : 0;
  sm[t] = v;
  __syncthreads();
  for (int s = 1; s < 512; s <<= 1){
    int add = (t >= s) ? sm[t - s] : 0;
    __syncthreads();
    sm[t] += add;
    __syncthreads();
  }
  if (t < NBLK1) ghist[bkt * NBLK1 + t] = sm[t] - v;   // exclusive
  if (t == 0) btotal[bkt] = sm[511];
}

// Pass 2b: exclusive scan of bucket totals -> bucketbase[NB+1].
__global__ __launch_bounds__(256) void k_bscan2(const int* __restrict__ btotal,
                                                int* __restrict__ bucketbase){
  __shared__ int sm[256];
  int t = threadIdx.x;
  int v = (t < NB) ? btotal[t] : 0;
  sm[t] = v;
  __syncthreads();
  for (int s = 1; s < 256; s <<= 1){
    int add = (t >= s) ? sm[t - s] : 0;
    __syncthreads();
    sm[t] += add;
    __syncthreads();
  }
  if (t < NB) bucketbase[t] = sm[t] - v;
  if (t == 0) bucketbase[NB] = sm[255];   // == NE
}

// Pass 3: scatter edges into bucket-partitioned pairs (dst<<32 | src).
// Only LDS atomics; global writes are plain stores.
__global__ __launch_bounds__(256) void k_scatter(const int* __restrict__ src,
                                                 const int* __restrict__ dst,
                                                 const int* __restrict__ ghist,
                                                 const int* __restrict__ bucketbase,
                                                 uint64_t* __restrict__ pairs){
  __shared__ int lcur[NB];
  int t = threadIdx.x, b = blockIdx.x;
  if (t < NB) lcur[t] = bucketbase[t] + ghist[t * NBLK1 + b];
  __syncthreads();
  #pragma unroll
  for (int i = 0; i < 16; i++){
    int e = b * EPB + i * 256 + t;
    if (e < NE){
      int s = src[e], d = dst[e];
      int pos = atomicAdd(&lcur[d >> 9], 1);
      pairs[pos] = ((uint64_t)(uint32_t)d << 32) | (uint32_t)s;
    }
  }
}

// Pass 4: per-bucket fine sort -> csr, rowstart, dis. One block per bucket.
__global__ __launch_bounds__(512) void k_bsort(const uint64_t* __restrict__ pairs,
                                               const int* __restrict__ bucketbase,
                                               int* __restrict__ csr,
                                               int* __restrict__ rowstart,
                                               float* __restrict__ dis){
  __shared__ int lcnt[512], lofs[512], sm[512];
  int t = threadIdx.x, bkt = blockIdx.x;
  int n0 = bkt << 9;
  int beg = bucketbase[bkt], end = bucketbase[bkt + 1];
  lcnt[t] = 0;
  __syncthreads();
  for (int i = beg + t; i < end; i += 512){
    int d = (int)(pairs[i] >> 32);
    atomicAdd(&lcnt[d - n0], 1);
  }
  __syncthreads();
  int v = lcnt[t];
  sm[t] = v;
  __syncthreads();
  for (int s = 1; s < 512; s <<= 1){
    int add = (t >= s) ? sm[t - s] : 0;
    __syncthreads();
    sm[t] += add;
    __syncthreads();
  }
  int excl = sm[t] - v;
  lofs[t] = excl;
  int n = n0 + t;
  if (n < NN){
    rowstart[n] = beg + excl;
    dis[n] = rsqrtf((float)(v + 1));
  }
  if (bkt == 0 && t == 0) rowstart[NN] = NE;
  __syncthreads();
  for (int i = beg + t; i < end; i += 512){
    uint64_t u = pairs[i];
    int d = (int)(u >> 32);
    int p = atomicAdd(&lofs[d - n0], 1);
    csr[beg + p] = (int)(uint32_t)u;
  }
}

// ---------------- weight transpose (+dtype convert): WT[c*128+k] = W[k][c] ----
__global__ void k_wt(const void* __restrict__ W, uint16_t* __restrict__ WT,
                     const int* __restrict__ flag){
  int idx = blockIdx.x * 256 + threadIdx.x;   // 64 blocks -> 16384
  int c = idx >> 7, k = idx & 127;
  WT[idx] = flag[0] ? f2bf(((const float*)W)[k * DD + c])
                    : ((const uint16_t*)W)[k * DD + c];
}

// bb[0..127] = b1 (bf16), bb[128..255] = b2 (bf16)
__global__ void k_bias(const void* __restrict__ b1, const void* __restrict__ b2,
                       uint16_t* __restrict__ bb, const int* __restrict__ flag){
  int t = threadIdx.x;   // 256
  const void* src = (t < 128) ? b1 : b2;
  int i = t & 127;
  bb[t] = flag[0] ? f2bf(((const float*)src)[i]) : ((const uint16_t*)src)[i];
}

// ---------------- X -> canonical bf16 copy ----------------
__global__ void k_cvt(const void* __restrict__ X, uint16_t* __restrict__ XB,
                      const int* __restrict__ flag){
  int i8 = blockIdx.x * 256 + threadIdx.x;    // 16-byte chunk; 6250*256 exact
  if (flag[0]){
    const floatx4* xf = (const floatx4*)X;
    floatx4 u = xf[i8 * 2], v = xf[i8 * 2 + 1];
    uint32x4 o;
    o.x = (uint32_t)f2bf(u.x) | ((uint32_t)f2bf(u.y) << 16);
    o.y = (uint32_t)f2bf(u.z) | ((uint32_t)f2bf(u.w) << 16);
    o.z = (uint32_t)f2bf(v.x) | ((uint32_t)f2bf(v.y) << 16);
    o.w = (uint32_t)f2bf(v.z) | ((uint32_t)f2bf(v.w) << 16);
    ((uint32x4*)XB)[i8] = o;
  } else {
    ((uint32x4*)XB)[i8] = ((const uint32x4*)X)[i8];
  }
}

// ---------------- GEMM: H = X * W (bf16 MFMA 16x16x32) ----------------
__global__ __launch_bounds__(256) void k_gemm(const uint16_t* __restrict__ X,
                                              const uint16_t* __restrict__ WT,
                                              uint16_t* __restrict__ H){
  __shared__ uint16_t lwt[128 * 136];   // +8 shorts pad -> 2-way bank alias (free)
  int t = threadIdx.x;
  const uint32_t* wt32 = (const uint32_t*)WT;
  #pragma unroll
  for (int i = 0; i < 32; i++){
    int uidx = t + 256 * i;
    uint32_t w2 = wt32[uidx];
    int el = uidx * 2;
    int c = el >> 7, k = el & 127;
    *(uint32_t*)&lwt[c * 136 + k] = w2;
  }
  __syncthreads();

  int wave = t >> 6, lane = t & 63;
  int m = lane & 15, q = lane >> 4;
  int rowbase = blockIdx.x * 64 + wave * 16;
  int ar = rowbase + m;
  if (ar >= NN) ar = 0;
  const short8* xrow = (const short8*)(X + (size_t)ar * DD);
  short8 a0 = xrow[q], a1 = xrow[q + 4], a2 = xrow[q + 8], a3 = xrow[q + 12];

  #pragma unroll
  for (int nt = 0; nt < 8; nt++){
    int c = nt * 16 + m;
    const uint16_t* bp = &lwt[c * 136 + q * 8];
    floatx4 acc = {0.f, 0.f, 0.f, 0.f};
    acc = __builtin_amdgcn_mfma_f32_16x16x32_bf16(a0, *(const short8*)(bp +  0), acc, 0, 0, 0);
    acc = __builtin_amdgcn_mfma_f32_16x16x32_bf16(a1, *(const short8*)(bp + 32), acc, 0, 0, 0);
    acc = __builtin_amdgcn_mfma_f32_16x16x32_bf16(a2, *(const short8*)(bp + 64), acc, 0, 0, 0);
    acc = __builtin_amdgcn_mfma_f32_16x16x32_bf16(a3, *(const short8*)(bp + 96), acc, 0, 0, 0);
    #pragma unroll
    for (int r = 0; r < 4; r++){
      int row = rowbase + q * 4 + r;
      if (row < NN) H[(size_t)row * DD + c] = f2bf(acc[r]);
    }
  }
}

// ---------------- aggregation: one wave per node, CSR gather ----------------
__global__ __launch_bounds__(256) void k_agg(const uint16_t* __restrict__ H,
                                             const int* __restrict__ rowstart,
                                             const int* __restrict__ csr,
                                             const float* __restrict__ dis,
                                             const uint16_t* __restrict__ bias,
                                             void* __restrict__ OUT,
                                             const int* __restrict__ flag,
                                             int is_final){
  int wave = threadIdx.x >> 6, lane = threadIdx.x & 63;
  int n = blockIdx.x * 4 + wave;
  if (n >= NN) return;
  float dn = dis[n];
  int beg = rowstart[n], end = rowstart[n + 1];
  uint32_t h2 = ((const uint32_t*)(H + (size_t)n * DD))[lane];
  float ss = dn * dn;
  float a0 = bf2f((uint16_t)(h2 & 0xffffu)) * ss;
  float a1 = bf2f((uint16_t)(h2 >> 16)) * ss;
  for (int j0 = beg; j0 < end; j0 += 64){
    int cnt = min(64, end - j0);
    int sj = 0; float dj = 0.f;
    if (lane < cnt){ sj = csr[j0 + lane]; dj = dis[sj]; }
    for (int jj = 0; jj < cnt; jj++){
      int s = __shfl(sj, jj);
      float coef = __shfl(dj, jj) * dn;
      uint32_t v = ((const uint32_t*)(H + (size_t)s * DD))[lane];
      a0 = fmaf(bf2f((uint16_t)(v & 0xffffu)), coef, a0);
      a1 = fmaf(bf2f((uint16_t)(v >> 16)), coef, a1);
    }
  }
  uint32_t b2 = ((const uint32_t*)bias)[lane];
  a0 = lrelu(a0 + bf2f((uint16_t)(b2 & 0xffffu)));
  a1 = lrelu(a1 + bf2f((uint16_t)(b2 >> 16)));
  if (is_final && flag[0]){
    floatx2 o = {a0, a1};
    ((floatx2*)((float*)OUT + (size_t)n * DD))[lane] = o;
  } else {
    ((uint32_t*)((uint16_t*)OUT + (size_t)n * DD))[lane] =
        (uint32_t)f2bf(a0) | ((uint32_t)f2bf(a1) << 16);
  }
}

extern "C" void kernel_launch(void* const* d_in, const int* in_sizes, int n_in,
                              void* d_out, int out_size, void* d_ws, size_t ws_size,
                              hipStream_t stream){
  const void* x  = d_in[0];
  const void* W1 = d_in[1];
  const void* b1 = d_in[2];
  const void* W2 = d_in[3];
  const void* b2 = d_in[4];
  const int* ei   = (const int*)d_in[5];
  const int* esrc = ei;
  const int* edst = ei + NE;

  char* ws = (char*)d_ws;
  float*    dis        = (float*)(ws + 0);                     // 400,000 B
  int*      rowstart   = (int*)(ws + 512ull * 1024);           // 400,004 B
  int*      flag       = (int*)(ws + 960ull * 1024);           // 4 B
  uint16_t* WT1        = (uint16_t*)(ws + 964ull * 1024);      // 32 KiB
  uint16_t* WT2        = (uint16_t*)(ws + 996ull * 1024);      // 32 KiB
  uint16_t* bb         = (uint16_t*)(ws + 1028ull * 1024);     // 512 B
  int*      ghist      = (int*)(ws + 1032ull * 1024);          // 306,544 B
  int*      btotal     = (int*)(ws + 1344ull * 1024);          // 784 B
  int*      bucketbase = (int*)(ws + 1348ull * 1024);          // 788 B
  int*      csr        = (int*)(ws + 2048ull * 1024);          // 6.4 MB
  uint16_t* hA         = (uint16_t*)(ws + 10240ull * 1024);    // 25.6 MB
  uint64_t* pairs      = (uint64_t*)hA;                        // aliases hA (dead before gemm1)
  uint16_t* xb         = (uint16_t*)(ws + 36864ull * 1024);    // 25.6 MB (also hB)
  uint16_t* hB         = xb;   // xb dead after gemm1; hB written by agg1 afterwards

  k_detect<<<1, 64, 0, stream>>>((const uint32_t*)x, flag);
  k_hist  <<<NBLK1, 256, 0, stream>>>(edst, ghist);
  k_bscan <<<NB, 512, 0, stream>>>(ghist, btotal);
  k_bscan2<<<1, 256, 0, stream>>>(btotal, bucketbase);
  k_scatter<<<NBLK1, 256, 0, stream>>>(esrc, edst, ghist, bucketbase, pairs);
  k_bsort <<<NB, 512, 0, stream>>>(pairs, bucketbase, csr, rowstart, dis);
  k_wt    <<<64, 256, 0, stream>>>(W1, WT1, flag);
  k_wt    <<<64, 256, 0, stream>>>(W2, WT2, flag);
  k_bias  <<<1, 256, 0, stream>>>(b1, b2, bb, flag);
  k_cvt   <<<6250, 256, 0, stream>>>(x, xb, flag);

  k_gemm<<<(NN + 63) / 64, 256, 0, stream>>>(xb, WT1, hA);
  k_agg <<<NN / 4, 256, 0, stream>>>(hA, rowstart, csr, dis, bb, hB, flag, 0);
  k_gemm<<<(NN + 63) / 64, 256, 0, stream>>>(hB, WT2, hA);
  k_agg <<<NN / 4, 256, 0, stream>>>(hA, rowstart, csr, dis, bb + 128, d_out, flag, 1);
}

// Round 4
// 321.638 us; speedup vs baseline: 1.7045x; 1.2362x over previous
//
#include <hip/hip_runtime.h>
#include <hip/hip_bf16.h>
#include <stdint.h>

#define NN 100000
#define NE 1600000
#define DD 128
#define NEG 0.01f
#define NB 196        // coarse buckets of 512 nodes (dst>>9)
#define EPB 4096      // edges per block in hist/scatter
#define NBLK1 391     // ceil(NE/EPB)

typedef __attribute__((ext_vector_type(8))) short short8;
typedef __attribute__((ext_vector_type(4))) float floatx4;
typedef __attribute__((ext_vector_type(2))) float floatx2;
typedef __attribute__((ext_vector_type(4))) uint32_t uint32x4;

__device__ __forceinline__ float bf2f(uint16_t u){
  return __uint_as_float(((uint32_t)u) << 16);
}
__device__ __forceinline__ uint16_t f2bf(float f){
  uint32_t i = __float_as_uint(f);
  return (uint16_t)((i + 0x7FFFu + ((i >> 16) & 1u)) >> 16);  // RNE
}
__device__ __forceinline__ float lrelu(float x){ return fmaxf(x, NEG * x); }

// ---------------- dtype detect: are float tensors f32 or bf16? ----------------
__global__ void k_detect(const uint32_t* __restrict__ xw, int* __restrict__ flag){
  int lane = threadIdx.x;
  uint32_t w = xw[lane];
  uint32_t e = (w >> 7) & 0xFFu;
  int plaus = (e >= 100u && e <= 134u) ? 1 : 0;
  unsigned long long b = __ballot(plaus);
  if (lane == 0) flag[0] = (__popcll(b) >= 48) ? 0 : 1;
}

// ---------------- CSR build: deterministic two-level counting sort ------------
__global__ __launch_bounds__(256) void k_hist(const int* __restrict__ dst,
                                              int* __restrict__ ghist){
  __shared__ int lh[NB];
  int t = threadIdx.x, b = blockIdx.x;
  if (t < NB) lh[t] = 0;
  __syncthreads();
  #pragma unroll
  for (int i = 0; i < 16; i++){
    int e = b * EPB + i * 256 + t;
    if (e < NE) atomicAdd(&lh[dst[e] >> 9], 1);
  }
  __syncthreads();
  if (t < NB) ghist[t * NBLK1 + b] = lh[t];
}

__global__ __launch_bounds__(512) void k_bscan(int* __restrict__ ghist,
                                               int* __restrict__ btotal){
  __shared__ int sm[512];
  int t = threadIdx.x, bkt = blockIdx.x;
  int v = (t < NBLK1) ? ghist[bkt * NBLK1 + t] : 0;
  sm[t] = v;
  __syncthreads();
  for (int s = 1; s < 512; s <<= 1){
    int add = (t >= s) ? sm[t - s] : 0;
    __syncthreads();
    sm[t] += add;
    __syncthreads();
  }
  if (t < NBLK1) ghist[bkt * NBLK1 + t] = sm[t] - v;   // exclusive
  if (t == 0) btotal[bkt] = sm[511];
}

__global__ __launch_bounds__(256) void k_bscan2(const int* __restrict__ btotal,
                                                int* __restrict__ bucketbase){
  __shared__ int sm[256];
  int t = threadIdx.x;
  int v = (t < NB) ? btotal[t] : 0;
  sm[t] = v;
  __syncthreads();
  for (int s = 1; s < 256; s <<= 1){
    int add = (t >= s) ? sm[t - s] : 0;
    __syncthreads();
    sm[t] += add;
    __syncthreads();
  }
  if (t < NB) bucketbase[t] = sm[t] - v;
  if (t == 0) bucketbase[NB] = sm[255];   // == NE
}

__global__ __launch_bounds__(256) void k_scatter(const int* __restrict__ src,
                                                 const int* __restrict__ dst,
                                                 const int* __restrict__ ghist,
                                                 const int* __restrict__ bucketbase,
                                                 uint64_t* __restrict__ pairs){
  __shared__ int lcur[NB];
  int t = threadIdx.x, b = blockIdx.x;
  if (t < NB) lcur[t] = bucketbase[t] + ghist[t * NBLK1 + b];
  __syncthreads();
  #pragma unroll
  for (int i = 0; i < 16; i++){
    int e = b * EPB + i * 256 + t;
    if (e < NE){
      int s = src[e], d = dst[e];
      int pos = atomicAdd(&lcur[d >> 9], 1);
      pairs[pos] = ((uint64_t)(uint32_t)d << 32) | (uint32_t)s;
    }
  }
}

__global__ __launch_bounds__(512) void k_bsort(const uint64_t* __restrict__ pairs,
                                               const int* __restrict__ bucketbase,
                                               int* __restrict__ csr,
                                               int* __restrict__ rowstart,
                                               float* __restrict__ dis){
  __shared__ int lcnt[512], lofs[512], sm[512];
  int t = threadIdx.x, bkt = blockIdx.x;
  int n0 = bkt << 9;
  int beg = bucketbase[bkt], end = bucketbase[bkt + 1];
  lcnt[t] = 0;
  __syncthreads();
  for (int i = beg + t; i < end; i += 512){
    int d = (int)(pairs[i] >> 32);
    atomicAdd(&lcnt[d - n0], 1);
  }
  __syncthreads();
  int v = lcnt[t];
  sm[t] = v;
  __syncthreads();
  for (int s = 1; s < 512; s <<= 1){
    int add = (t >= s) ? sm[t - s] : 0;
    __syncthreads();
    sm[t] += add;
    __syncthreads();
  }
  int excl = sm[t] - v;
  lofs[t] = excl;
  int n = n0 + t;
  if (n < NN){
    rowstart[n] = beg + excl;
    dis[n] = rsqrtf((float)(v + 1));
  }
  if (bkt == 0 && t == 0) rowstart[NN] = NE;
  __syncthreads();
  for (int i = beg + t; i < end; i += 512){
    uint64_t u = pairs[i];
    int d = (int)(u >> 32);
    int p = atomicAdd(&lofs[d - n0], 1);
    csr[beg + p] = (int)(uint32_t)u;
  }
}

// ---------------- weight transpose (+dtype convert): WT[c*128+k] = W[k][c] ----
__global__ void k_wt(const void* __restrict__ W, uint16_t* __restrict__ WT,
                     const int* __restrict__ flag){
  int idx = blockIdx.x * 256 + threadIdx.x;   // 64 blocks -> 16384
  int c = idx >> 7, k = idx & 127;
  WT[idx] = flag[0] ? f2bf(((const float*)W)[k * DD + c])
                    : ((const uint16_t*)W)[k * DD + c];
}

// bb[0..127] = b1 (bf16), bb[128..255] = b2 (bf16)
__global__ void k_bias(const void* __restrict__ b1, const void* __restrict__ b2,
                       uint16_t* __restrict__ bb, const int* __restrict__ flag){
  int t = threadIdx.x;   // 256
  const void* src = (t < 128) ? b1 : b2;
  int i = t & 127;
  bb[t] = flag[0] ? f2bf(((const float*)src)[i]) : ((const uint16_t*)src)[i];
}

// ---------------- X -> canonical bf16 copy ----------------
__global__ void k_cvt(const void* __restrict__ X, uint16_t* __restrict__ XB,
                      const int* __restrict__ flag){
  int i8 = blockIdx.x * 256 + threadIdx.x;    // 16-byte chunk; 6250*256 exact
  if (flag[0]){
    const floatx4* xf = (const floatx4*)X;
    floatx4 u = xf[i8 * 2], v = xf[i8 * 2 + 1];
    uint32x4 o;
    o.x = (uint32_t)f2bf(u.x) | ((uint32_t)f2bf(u.y) << 16);
    o.y = (uint32_t)f2bf(u.z) | ((uint32_t)f2bf(u.w) << 16);
    o.z = (uint32_t)f2bf(v.x) | ((uint32_t)f2bf(v.y) << 16);
    o.w = (uint32_t)f2bf(v.z) | ((uint32_t)f2bf(v.w) << 16);
    ((uint32x4*)XB)[i8] = o;
  } else {
    ((uint32x4*)XB)[i8] = ((const uint32x4*)X)[i8];
  }
}

// ---------------- GEMM: H = X * W (bf16 MFMA 16x16x32) ----------------
__global__ __launch_bounds__(256) void k_gemm(const uint16_t* __restrict__ X,
                                              const uint16_t* __restrict__ WT,
                                              uint16_t* __restrict__ H){
  __shared__ uint16_t lwt[128 * 136];   // +8 shorts pad -> 2-way bank alias (free)
  int t = threadIdx.x;
  const uint32_t* wt32 = (const uint32_t*)WT;
  #pragma unroll
  for (int i = 0; i < 32; i++){
    int uidx = t + 256 * i;
    uint32_t w2 = wt32[uidx];
    int el = uidx * 2;
    int c = el >> 7, k = el & 127;
    *(uint32_t*)&lwt[c * 136 + k] = w2;
  }
  __syncthreads();

  int wave = t >> 6, lane = t & 63;
  int m = lane & 15, q = lane >> 4;
  int rowbase = blockIdx.x * 64 + wave * 16;
  int ar = rowbase + m;
  if (ar >= NN) ar = 0;
  const short8* xrow = (const short8*)(X + (size_t)ar * DD);
  short8 a0 = xrow[q], a1 = xrow[q + 4], a2 = xrow[q + 8], a3 = xrow[q + 12];

  #pragma unroll
  for (int nt = 0; nt < 8; nt++){
    int c = nt * 16 + m;
    const uint16_t* bp = &lwt[c * 136 + q * 8];
    floatx4 acc = {0.f, 0.f, 0.f, 0.f};
    acc = __builtin_amdgcn_mfma_f32_16x16x32_bf16(a0, *(const short8*)(bp +  0), acc, 0, 0, 0);
    acc = __builtin_amdgcn_mfma_f32_16x16x32_bf16(a1, *(const short8*)(bp + 32), acc, 0, 0, 0);
    acc = __builtin_amdgcn_mfma_f32_16x16x32_bf16(a2, *(const short8*)(bp + 64), acc, 0, 0, 0);
    acc = __builtin_amdgcn_mfma_f32_16x16x32_bf16(a3, *(const short8*)(bp + 96), acc, 0, 0, 0);
    #pragma unroll
    for (int r = 0; r < 4; r++){
      int row = rowbase + q * 4 + r;
      if (row < NN) H[(size_t)row * DD + c] = f2bf(acc[r]);
    }
  }
}

// ---------------- aggregation: one wave/node, 4 edges per dwordx4 gather ------
// lane = grp*16 + sl: grp = edge-in-chunk, sl = dim-slice (dims 8sl..8sl+7).
// Per chunk: 1 KB wave-load (4 edge rows), LDS b64 broadcast of (src,coef),
// 2-deep pipeline; butterfly xor16/32 folds groups at the end.
__global__ __launch_bounds__(256) void k_agg(const uint16_t* __restrict__ H,
                                             const int* __restrict__ rowstart,
                                             const int* __restrict__ csr,
                                             const float* __restrict__ dis,
                                             const uint16_t* __restrict__ bias,
                                             void* __restrict__ OUT,
                                             const int* __restrict__ flag,
                                             int is_final){
  __shared__ int2 ebuf[4][68];   // 64 + 4 zero-pad (pipeline overread)
  int wave = threadIdx.x >> 6, lane = threadIdx.x & 63;
  int grp = lane >> 4, sl = lane & 15;
  if (lane < 4) ebuf[wave][64 + lane] = make_int2(0, 0);
  int n = blockIdx.x * 4 + wave;
  if (n >= NN) return;
  float dn = dis[n];
  int beg = rowstart[n], end = rowstart[n + 1];

  float acc[8] = {0.f,0.f,0.f,0.f,0.f,0.f,0.f,0.f};
  uint32x4 hn = ((const uint32x4*)(H + (size_t)n * DD))[sl];   // self row slice

  for (int j0 = beg; j0 < end; j0 += 64){
    int cnt = min(64, end - j0);
    int sj = 0; float cf = 0.f;
    if (lane < cnt){ sj = csr[j0 + lane]; cf = dis[sj] * dn; }
    ebuf[wave][lane] = make_int2(sj, __float_as_int(cf));
    int chunks = (cnt + 3) >> 2;
    int2 ea = ebuf[wave][grp];
    uint32x4 va = *(const uint32x4*)(H + (size_t)ea.x * DD + sl * 8);
    for (int c = 0; c < chunks; c++){
      int2 eb = ebuf[wave][c * 4 + 4 + grp];
      uint32x4 vb = *(const uint32x4*)(H + (size_t)eb.x * DD + sl * 8);
      float cf2 = __int_as_float(ea.y);
      acc[0] = fmaf(__uint_as_float(va.x << 16),         cf2, acc[0]);
      acc[1] = fmaf(__uint_as_float(va.x & 0xffff0000u), cf2, acc[1]);
      acc[2] = fmaf(__uint_as_float(va.y << 16),         cf2, acc[2]);
      acc[3] = fmaf(__uint_as_float(va.y & 0xffff0000u), cf2, acc[3]);
      acc[4] = fmaf(__uint_as_float(va.z << 16),         cf2, acc[4]);
      acc[5] = fmaf(__uint_as_float(va.z & 0xffff0000u), cf2, acc[5]);
      acc[6] = fmaf(__uint_as_float(va.w << 16),         cf2, acc[6]);
      acc[7] = fmaf(__uint_as_float(va.w & 0xffff0000u), cf2, acc[7]);
      ea = eb; va = vb;
    }
  }
  #pragma unroll
  for (int j = 0; j < 8; j++){
    acc[j] += __shfl_xor(acc[j], 16, 64);
    acc[j] += __shfl_xor(acc[j], 32, 64);
  }
  float ss = dn * dn;
  uint32x4 bv = ((const uint32x4*)bias)[sl];
  float o[8];
  o[0] = lrelu(fmaf(__uint_as_float(hn.x << 16),         ss, acc[0]) + __uint_as_float(bv.x << 16));
  o[1] = lrelu(fmaf(__uint_as_float(hn.x & 0xffff0000u), ss, acc[1]) + __uint_as_float(bv.x & 0xffff0000u));
  o[2] = lrelu(fmaf(__uint_as_float(hn.y << 16),         ss, acc[2]) + __uint_as_float(bv.y << 16));
  o[3] = lrelu(fmaf(__uint_as_float(hn.y & 0xffff0000u), ss, acc[3]) + __uint_as_float(bv.y & 0xffff0000u));
  o[4] = lrelu(fmaf(__uint_as_float(hn.z << 16),         ss, acc[4]) + __uint_as_float(bv.z << 16));
  o[5] = lrelu(fmaf(__uint_as_float(hn.z & 0xffff0000u), ss, acc[5]) + __uint_as_float(bv.z & 0xffff0000u));
  o[6] = lrelu(fmaf(__uint_as_float(hn.w << 16),         ss, acc[6]) + __uint_as_float(bv.w << 16));
  o[7] = lrelu(fmaf(__uint_as_float(hn.w & 0xffff0000u), ss, acc[7]) + __uint_as_float(bv.w & 0xffff0000u));

  if (is_final && flag[0]){
    float* orow = (float*)OUT + (size_t)n * DD + sl * 8;
    if (lane < 16){
      floatx4 v = {o[0], o[1], o[2], o[3]};
      ((floatx4*)orow)[0] = v;
    } else if (lane < 32){
      floatx4 v = {o[4], o[5], o[6], o[7]};
      ((floatx4*)orow)[1] = v;
    }
  } else if (lane < 16){
    uint32x4 pv;
    pv.x = (uint32_t)f2bf(o[0]) | ((uint32_t)f2bf(o[1]) << 16);
    pv.y = (uint32_t)f2bf(o[2]) | ((uint32_t)f2bf(o[3]) << 16);
    pv.z = (uint32_t)f2bf(o[4]) | ((uint32_t)f2bf(o[5]) << 16);
    pv.w = (uint32_t)f2bf(o[6]) | ((uint32_t)f2bf(o[7]) << 16);
    *(uint32x4*)((uint16_t*)OUT + (size_t)n * DD + sl * 8) = pv;
  }
}

extern "C" void kernel_launch(void* const* d_in, const int* in_sizes, int n_in,
                              void* d_out, int out_size, void* d_ws, size_t ws_size,
                              hipStream_t stream){
  const void* x  = d_in[0];
  const void* W1 = d_in[1];
  const void* b1 = d_in[2];
  const void* W2 = d_in[3];
  const void* b2 = d_in[4];
  const int* ei   = (const int*)d_in[5];
  const int* esrc = ei;
  const int* edst = ei + NE;

  char* ws = (char*)d_ws;
  float*    dis        = (float*)(ws + 0);                     // 400,000 B
  int*      rowstart   = (int*)(ws + 512ull * 1024);           // 400,004 B
  int*      flag       = (int*)(ws + 960ull * 1024);           // 4 B
  uint16_t* WT1        = (uint16_t*)(ws + 964ull * 1024);      // 32 KiB
  uint16_t* WT2        = (uint16_t*)(ws + 996ull * 1024);      // 32 KiB
  uint16_t* bb         = (uint16_t*)(ws + 1028ull * 1024);     // 512 B
  int*      ghist      = (int*)(ws + 1032ull * 1024);          // 306,544 B
  int*      btotal     = (int*)(ws + 1344ull * 1024);          // 784 B
  int*      bucketbase = (int*)(ws + 1348ull * 1024);          // 788 B
  int*      csr        = (int*)(ws + 2048ull * 1024);          // 6.4 MB
  uint16_t* hA         = (uint16_t*)(ws + 10240ull * 1024);    // 25.6 MB
  uint64_t* pairs      = (uint64_t*)hA;                        // aliases hA (dead before gemm1)
  uint16_t* xb         = (uint16_t*)(ws + 36864ull * 1024);    // 25.6 MB (also hB)
  uint16_t* hB         = xb;   // xb dead after gemm1; hB written by agg1 afterwards

  k_detect<<<1, 64, 0, stream>>>((const uint32_t*)x, flag);
  k_hist  <<<NBLK1, 256, 0, stream>>>(edst, ghist);
  k_bscan <<<NB, 512, 0, stream>>>(ghist, btotal);
  k_bscan2<<<1, 256, 0, stream>>>(btotal, bucketbase);
  k_scatter<<<NBLK1, 256, 0, stream>>>(esrc, edst, ghist, bucketbase, pairs);
  k_bsort <<<NB, 512, 0, stream>>>(pairs, bucketbase, csr, rowstart, dis);
  k_wt    <<<64, 256, 0, stream>>>(W1, WT1, flag);
  k_wt    <<<64, 256, 0, stream>>>(W2, WT2, flag);
  k_bias  <<<1, 256, 0, stream>>>(b1, b2, bb, flag);
  k_cvt   <<<6250, 256, 0, stream>>>(x, xb, flag);

  k_gemm<<<(NN + 63) / 64, 256, 0, stream>>>(xb, WT1, hA);
  k_agg <<<NN / 4, 256, 0, stream>>>(hA, rowstart, csr, dis, bb, hB, flag, 0);
  k_gemm<<<(NN + 63) / 64, 256, 0, stream>>>(hB, WT2, hA);
  k_agg <<<NN / 4, 256, 0, stream>>>(hA, rowstart, csr, dis, bb + 128, d_out, flag, 1);
}